// Round 5
// baseline (512.657 us; speedup 1.0000x reference)
//
#include <hip/hip_runtime.h>
#include <hip/hip_bf16.h>

#define NN 50000
#define EE 600000
#define RR 8
#define NSEG (NN*RR)                     // 400000
#define NB_SCAN ((NSEG + 1023)/1024)     // 391

typedef unsigned int u32;
typedef __attribute__((ext_vector_type(8))) short bf16x8;
typedef __attribute__((ext_vector_type(4))) float f32x4;
typedef __attribute__((ext_vector_type(4))) u32 u32x4;

// fp32 -> bf16 round-to-nearest-even (finite inputs only)
__device__ inline unsigned short f2bf(float f){
  u32 u = __float_as_uint(f);
  u32 r = (u + 0x7fffu + ((u >> 16) & 1u)) >> 16;
  return (unsigned short)r;
}
__device__ inline float bf2f(unsigned short b){ return __uint_as_float((u32)b << 16); }

// Wave-level LDS fence: drain ds ops, forbid compiler motion across (rule #18).
#define WAVE_FENCE() do{ __builtin_amdgcn_sched_barrier(0); \
  asm volatile("s_waitcnt lgkmcnt(0)" ::: "memory"); \
  __builtin_amdgcn_sched_barrier(0); }while(0)

// ---------------- conversion: fp32 -> bf16, 4 elems/thread ----------------
__global__ void cvt_k(const float* __restrict__ in, unsigned short* __restrict__ out, int n4){
  int i = blockIdx.x * 256 + threadIdx.x;
  if (i >= n4) return;
  float4 v = ((const float4*)in)[i];
  ushort4 o;
  o.x = f2bf(v.x); o.y = f2bf(v.y); o.z = f2bf(v.z); o.w = f2bf(v.w);
  ((ushort4*)out)[i] = o;
}

// ---------------- pack B (W stack) into MFMA fragment order ----------------
// frag id = k32*8 + nf; within frag: lane*8 + i
// element: B[k32*32 + (lane>>4)*8 + i][nf*16 + (lane&15)]
__global__ void pack_k(const float* __restrict__ Wrel, const float* __restrict__ root,
                       short* __restrict__ Bp, int nk32, int krel){
  int tid = blockIdx.x * 256 + threadIdx.x;
  if (tid >= nk32 * 512) return;
  int lane = tid & 63;
  int nf   = (tid >> 6) & 7;
  int k32  = tid >> 9;
  int col  = nf * 16 + (lane & 15);
  short vals[8];
#pragma unroll
  for (int i = 0; i < 8; ++i){
    int kk = k32 * 32 + ((lane >> 4) << 3) + i;
    float f = (kk < krel) ? Wrel[(size_t)kk * 128 + col]
                          : root[(size_t)(kk - krel) * 128 + col];
    vals[i] = (short)f2bf(f);
  }
  *(bf16x8*)(Bp + (size_t)tid * 8) = *(const bf16x8*)vals;
}

// ---------------- CSR build (relation-major: seg = r*NN + dst) -------------
__global__ void count_k(const int* __restrict__ dst, const int* __restrict__ et,
                        u32* __restrict__ cnt){
  int e = blockIdx.x * 256 + threadIdx.x;
  if (e >= EE) return;
  atomicAdd(&cnt[(size_t)et[e] * NN + dst[e]], 1u);
}

__global__ void scan1_k(const u32* __restrict__ cnt, u32* __restrict__ offs, u32* __restrict__ bsum){
  __shared__ u32 s[512];
  int t = threadIdx.x;                       // 256 threads
  int base = blockIdx.x * 1024 + t * 4;
  u32 loc[4]; u32 sum = 0;
#pragma unroll
  for (int i = 0; i < 4; ++i){ loc[i] = (base + i < NSEG) ? cnt[base + i] : 0u; sum += loc[i]; }
  int pb = 0;
  s[t] = sum; __syncthreads();
  for (int off = 1; off < 256; off <<= 1){
    u32 v = s[pb * 256 + t];
    if (t >= off) v += s[pb * 256 + t - off];
    s[(pb ^ 1) * 256 + t] = v; pb ^= 1; __syncthreads();
  }
  u32 incl = s[pb * 256 + t];
  u32 excl = incl - sum;
  if (t == 255) bsum[blockIdx.x] = incl;
  u32 run = excl;
#pragma unroll
  for (int i = 0; i < 4; ++i){ if (base + i < NSEG) offs[base + i] = run; run += loc[i]; }
}

__global__ void scan2_k(u32* __restrict__ bsum){
  __shared__ u32 s[1024];
  int t = threadIdx.x;                       // 512 threads
  u32 v = (t < NB_SCAN) ? bsum[t] : 0u;
  int pb = 0;
  s[t] = v; __syncthreads();
  for (int off = 1; off < 512; off <<= 1){
    u32 x = s[pb * 512 + t];
    if (t >= off) x += s[pb * 512 + t - off];
    s[(pb ^ 1) * 512 + t] = x; pb ^= 1; __syncthreads();
  }
  u32 incl = s[pb * 512 + t];
  if (t < NB_SCAN) bsum[t] = incl - v;       // exclusive
}

__global__ void scan3_k(u32* __restrict__ offs, const u32* __restrict__ bsum){
  int t = threadIdx.x;
  int base = blockIdx.x * 1024 + t * 4;
  u32 add = bsum[blockIdx.x];
#pragma unroll
  for (int i = 0; i < 4; ++i){ if (base + i < NSEG) offs[base + i] += add; }
  if (blockIdx.x == 0 && t == 0) offs[NSEG] = EE;
}

// fill: packed edge record src | ((dst&15)<<16); reuse cnt as cursor (atomicSub)
__global__ void fill_k(const int* __restrict__ src, const int* __restrict__ dst,
                       const int* __restrict__ et, const u32* __restrict__ offs,
                       u32* __restrict__ cnt, u32* __restrict__ elist){
  int e = blockIdx.x * 256 + threadIdx.x;
  if (e >= EE) return;
  int d = dst[e];
  int s = et[e] * NN + d;
  u32 p = atomicSub(&cnt[s], 1u);
  elist[offs[s] + p - 1] = (u32)src[e] | ((u32)(d & 15) << 16);
}

// ---------------- res projection: resb = bf16(x @ res_w + res_b) ----------
// LDS-free: A-fragments loaded directly from global.
__launch_bounds__(256, 4)
__global__ void resg_k(const unsigned short* __restrict__ xb, const short* __restrict__ Bp,
                       const float* __restrict__ rb, unsigned short* __restrict__ resb){
  const int tid = threadIdx.x;
  const int w = tid >> 6, l = tid & 63;
  const int sub = l >> 4, llr = l & 15;
  const int rowbase = blockIdx.x * 64 + w * 16;
  int vr = rowbase + llr; if (vr > NN - 1) vr = NN - 1;
  f32x4 acc[8] = {};
#pragma unroll
  for (int t = 0; t < 4; ++t){
    bf16x8 af = *(const bf16x8*)(xb + (size_t)vr * 128 + (t * 4 + sub) * 8);
    const short* bb = Bp + (size_t)(t * 8) * 512 + l * 8;
#pragma unroll
    for (int nf = 0; nf < 8; ++nf){
      bf16x8 bq = *(const bf16x8*)(bb + nf * 512);
      acc[nf] = __builtin_amdgcn_mfma_f32_16x16x32_bf16(af, bq, acc[nf], 0, 0, 0);
    }
  }
  const int lr = l >> 4, lc = l & 15;
#pragma unroll
  for (int nf = 0; nf < 8; ++nf){
    int col = nf * 16 + lc;
    float bv = rb[col];
#pragma unroll
    for (int r = 0; r < 4; ++r){
      int row = rowbase + lr * 4 + r;
      if (row < NN) resb[(size_t)row * 128 + col] = f2bf(acc[nf][r] + bv);
    }
  }
}

// ------- fused RGCN layer: shfl-CSR gather -> regs -> LDS -> MFMA ----------
// out[v,:] = resb[v,:] + relu( [mean_r(h[src])..., h[v]] @ Bp + bias )
// 8-lane groups: group g owns wave rows 2g, 2g+1.
// Edge loop is EXEC-UNIFORM (bound = wave-max cnt, contributions masked) so
// all __shfl sources are active lanes.
template<int OUTMODE>
__launch_bounds__(256, 3)
__global__ void fused_k(const u32* __restrict__ offs, const u32* __restrict__ elist,
                        const unsigned short* __restrict__ h,
                        const short* __restrict__ Bp,
                        const float* __restrict__ bias,
                        const unsigned short* __restrict__ resb,
                        float* __restrict__ outf, unsigned short* __restrict__ outb){
  __shared__ short Alds[64 * 128];           // 16 KB; each wave owns a 16x128 slice
  const int tid = threadIdx.x;
  const int w = tid >> 6, l = tid & 63;
  const int sub = l >> 4, llr = l & 15;      // MFMA-read roles
  const int g = l >> 3, ll8 = l & 7;         // gather roles: 8 groups x 8 lanes
  const int rowbase = blockIdx.x * 64 + w * 16;
  short* Aw = Alds + w * 16 * 128;
  f32x4 acc[8] = {};

#pragma unroll 1
  for (int kt = 0; kt < 9; ++kt){
    if (kt < 8){
      // --- register-resident CSR walk (uniform control flow) ---
      int sb = kt * NN + rowbase;
      int oidx = sb + (l < 16 ? l : 16); if (oidx > NSEG) oidx = NSEG;
      u32 offsv = offs[oidx];
      u32 beg16 = __shfl(offsv, 0);
      u32 gb = __shfl(offsv, g * 2);
      u32 gm = __shfl(offsv, g * 2 + 1);
      u32 ge = __shfl(offsv, g * 2 + 2);
      int cnt = (int)(ge - gb);
      int base = (int)(gb - beg16);
      int dr0 = (int)(gm - gb), dr1 = (int)(ge - gm);
      u32 e32v = elist[beg16 + l];           // wave's first 64 edges, coalesced
      int cntmax = cnt;
      cntmax = max(cntmax, __shfl_xor(cntmax, 8));
      cntmax = max(cntmax, __shfl_xor(cntmax, 16));
      cntmax = max(cntmax, __shfl_xor(cntmax, 32));

      float s0[16], s1[16];
#pragma unroll
      for (int i = 0; i < 16; ++i){ s0[i] = 0.f; s1[i] = 0.f; }

      // prefetch edge 0 (clamped index; value masked later if invalid)
      int idxA = base + (0 < cnt ? 0 : cnt - 1);
      u32 eA = __shfl(e32v, idxA & 63);
      if (idxA >= 64) eA = elist[beg16 + idxA];
      u32x4 a0, a1;
      { const unsigned short* rp = h + (size_t)(eA & 0xffffu) * 128 + ll8 * 16;
        a0 = *(const u32x4*)rp; a1 = *(const u32x4*)(rp + 8); }

#pragma unroll 1
      for (int j = 0; j < cntmax; ++j){
        u32 eB = 0; u32x4 b0 = {}, b1 = {};
        if (j + 1 < cntmax){                 // wave-uniform branch
          int idx = base + (j + 1 < cnt ? j + 1 : cnt - 1);
          u32 t_ = __shfl(e32v, idx & 63);
          eB = (idx >= 64) ? elist[beg16 + idx] : t_;
          const unsigned short* rp = h + (size_t)(eB & 0xffffu) * 128 + ll8 * 16;
          b0 = *(const u32x4*)rp; b1 = *(const u32x4*)(rp + 8);
        }
        u32 vm = (j < cnt) ? 0xffffffffu : 0u;
        u32 modd = 0u - ((eA >> 16) & 1u);
        u32 m1 = vm & modd, m0 = vm & ~modd;
#pragma unroll
        for (int i = 0; i < 4; ++i){
          u32 lo = a0[i] << 16, hi = a0[i] & 0xffff0000u;
          s0[2*i]   += __uint_as_float(lo & m0); s1[2*i]   += __uint_as_float(lo & m1);
          s0[2*i+1] += __uint_as_float(hi & m0); s1[2*i+1] += __uint_as_float(hi & m1);
        }
#pragma unroll
        for (int i = 0; i < 4; ++i){
          u32 lo = a1[i] << 16, hi = a1[i] & 0xffff0000u;
          s0[8+2*i]   += __uint_as_float(lo & m0); s1[8+2*i]   += __uint_as_float(lo & m1);
          s0[8+2*i+1] += __uint_as_float(hi & m0); s1[8+2*i+1] += __uint_as_float(hi & m1);
        }
        eA = eB; a0 = b0; a1 = b1;
      }
      // --- write the group's two rows (mean, bf16, chunk-XOR swizzle) ---
      float inv0 = dr0 ? __builtin_amdgcn_rcpf((float)dr0) : 0.f;
      float inv1 = dr1 ? __builtin_amdgcn_rcpf((float)dr1) : 0.f;
      int r0 = 2 * g, r1 = 2 * g + 1;
      u32x4 pk;
#pragma unroll
      for (int i = 0; i < 4; ++i)
        pk[i] = (u32)f2bf(s0[2*i] * inv0) | ((u32)f2bf(s0[2*i+1] * inv0) << 16);
      *(u32x4*)(Aw + r0 * 128 + ((2*ll8) ^ r0) * 8) = pk;
#pragma unroll
      for (int i = 0; i < 4; ++i)
        pk[i] = (u32)f2bf(s0[8+2*i] * inv0) | ((u32)f2bf(s0[8+2*i+1] * inv0) << 16);
      *(u32x4*)(Aw + r0 * 128 + ((2*ll8+1) ^ r0) * 8) = pk;
#pragma unroll
      for (int i = 0; i < 4; ++i)
        pk[i] = (u32)f2bf(s1[2*i] * inv1) | ((u32)f2bf(s1[2*i+1] * inv1) << 16);
      *(u32x4*)(Aw + r1 * 128 + ((2*ll8) ^ r1) * 8) = pk;
#pragma unroll
      for (int i = 0; i < 4; ++i)
        pk[i] = (u32)f2bf(s1[8+2*i] * inv1) | ((u32)f2bf(s1[8+2*i+1] * inv1) << 16);
      *(u32x4*)(Aw + r1 * 128 + ((2*ll8+1) ^ r1) * 8) = pk;

      WAVE_FENCE();
    }
    // --- MFMA phase ---
    int vr = rowbase + llr; if (vr > NN - 1) vr = NN - 1;
#pragma unroll
    for (int t = 0; t < 4; ++t){
      bf16x8 af;
      if (kt < 8){
        int p = (t * 4 + sub) ^ llr;
        af = *(const bf16x8*)(Aw + llr * 128 + p * 8);
      } else {
        af = *(const bf16x8*)(h + (size_t)vr * 128 + (t * 4 + sub) * 8);
      }
      const short* bb = Bp + (size_t)(((size_t)kt * 4 + t) * 8) * 512 + l * 8;
#pragma unroll
      for (int nf = 0; nf < 8; ++nf){
        bf16x8 bq = *(const bf16x8*)(bb + nf * 512);
        acc[nf] = __builtin_amdgcn_mfma_f32_16x16x32_bf16(af, bq, acc[nf], 0, 0, 0);
      }
    }
    if (kt < 8) WAVE_FENCE();
  }

  const int lr = l >> 4, lc = l & 15;
#pragma unroll
  for (int nf = 0; nf < 8; ++nf){
    int col = nf * 16 + lc;
    float bv = bias[col];
#pragma unroll
    for (int r = 0; r < 4; ++r){
      int row = rowbase + lr * 4 + r;
      if (row < NN){
        float v = acc[nf][r] + bv;
        v = bf2f(resb[(size_t)row * 128 + col]) + fmaxf(v, 0.f);
        if (OUTMODE == 1) outb[(size_t)row * 128 + col] = f2bf(v);
        else              outf[(size_t)row * 128 + col] = v;
      }
    }
  }
}

extern "C" void kernel_launch(void* const* d_in, const int* in_sizes, int n_in,
                              void* d_out, int out_size, void* d_ws, size_t ws_size,
                              hipStream_t stream){
  const float* x  = (const float*)d_in[0];
  const int*   ei = (const int*)d_in[1];
  const int*   et = (const int*)d_in[2];
  const float* W1 = (const float*)d_in[3];
  const float* r1 = (const float*)d_in[4];
  const float* b1 = (const float*)d_in[5];
  const float* W2 = (const float*)d_in[6];
  const float* r2 = (const float*)d_in[7];
  const float* b2 = (const float*)d_in[8];
  const float* W3 = (const float*)d_in[9];
  const float* r3 = (const float*)d_in[10];
  const float* b3 = (const float*)d_in[11];
  const float* rw = (const float*)d_in[12];
  const float* rb = (const float*)d_in[13];
  const int* srcv = ei;
  const int* dstv = ei + EE;

  char* p = (char*)d_ws;
  auto take = [&](size_t b)->char*{ char* q = p; p += (b + 255) & ~(size_t)255; return q; };
  unsigned short* xb   = (unsigned short*)take((size_t)NN * 128 * 2);
  unsigned short* h1   = (unsigned short*)take((size_t)NN * 128 * 2);
  unsigned short* h2   = (unsigned short*)take((size_t)NN * 128 * 2);
  unsigned short* resb = (unsigned short*)take((size_t)NN * 128 * 2);
  short* Bp1 = (short*)take(36 * 4096 * 2);
  short* Bp2 = (short*)take(36 * 4096 * 2);
  short* Bp3 = (short*)take(36 * 4096 * 2);
  short* BpR = (short*)take(4 * 4096 * 2);
  u32* cnt   = (u32*)take((size_t)NSEG * 4);
  u32* offs  = (u32*)take((size_t)(NSEG + 1) * 4);
  u32* elist = (u32*)take((size_t)(EE + 64) * 4);   // padded for wave preload
  u32* bsum  = (u32*)take((size_t)NB_SCAN * 4);

  hipMemsetAsync(cnt, 0, (size_t)NSEG * 4, stream);

  // conversions + weight packing (once)
  cvt_k<<<(NN * 128 / 4 + 255) / 256, 256, 0, stream>>>(x, xb, NN * 128 / 4);
  pack_k<<<(36 * 512 + 255) / 256, 256, 0, stream>>>(W1, r1, Bp1, 36, 1024);
  pack_k<<<(36 * 512 + 255) / 256, 256, 0, stream>>>(W2, r2, Bp2, 36, 1024);
  pack_k<<<(36 * 512 + 255) / 256, 256, 0, stream>>>(W3, r3, Bp3, 36, 1024);
  pack_k<<<(4 * 512 + 255) / 256, 256, 0, stream>>>(nullptr, rw, BpR, 4, 0);

  // CSR over segments (etype*NN + dst), once for all layers
  count_k<<<(EE + 255) / 256, 256, 0, stream>>>(dstv, et, cnt);
  scan1_k<<<NB_SCAN, 256, 0, stream>>>(cnt, offs, bsum);
  scan2_k<<<1, 512, 0, stream>>>(bsum);
  scan3_k<<<NB_SCAN, 256, 0, stream>>>(offs, bsum);
  fill_k<<<(EE + 255) / 256, 256, 0, stream>>>(srcv, dstv, et, offs, cnt, elist);

  const int GB = (NN + 63) / 64;  // 782

  // res = bf16(x @ res_w + res_b)
  resg_k<<<GB, 256, 0, stream>>>(xb, BpR, rb, resb);

  // fused layers
  fused_k<1><<<GB, 256, 0, stream>>>(offs, elist, xb, Bp1, b1, resb, nullptr, h1);
  fused_k<1><<<GB, 256, 0, stream>>>(offs, elist, h1, Bp2, b2, resb, nullptr, h2);
  fused_k<2><<<GB, 256, 0, stream>>>(offs, elist, h2, Bp3, b3, resb, (float*)d_out, nullptr);
}

// Round 6
// 452.184 us; speedup vs baseline: 1.1337x; 1.1337x over previous
//
#include <hip/hip_runtime.h>
#include <hip/hip_bf16.h>

#define NN 50000
#define EE 600000
#define RR 8
#define NSEG (NN*RR)                     // 400000
#define NB_SCAN ((NSEG + 1023)/1024)     // 391

typedef unsigned int u32;
typedef __attribute__((ext_vector_type(8))) short bf16x8;
typedef __attribute__((ext_vector_type(4))) float f32x4;
typedef __attribute__((ext_vector_type(4))) u32 u32x4;

// fp32 -> bf16 round-to-nearest-even (finite inputs only)
__device__ inline unsigned short f2bf(float f){
  u32 u = __float_as_uint(f);
  u32 r = (u + 0x7fffu + ((u >> 16) & 1u)) >> 16;
  return (unsigned short)r;
}
__device__ inline float bf2f(unsigned short b){ return __uint_as_float((u32)b << 16); }

// ---------------- conversion: fp32 -> bf16, 4 elems/thread ----------------
__global__ void cvt_k(const float* __restrict__ in, unsigned short* __restrict__ out, int n4){
  int i = blockIdx.x * 256 + threadIdx.x;
  if (i >= n4) return;
  float4 v = ((const float4*)in)[i];
  ushort4 o;
  o.x = f2bf(v.x); o.y = f2bf(v.y); o.z = f2bf(v.z); o.w = f2bf(v.w);
  ((ushort4*)out)[i] = o;
}

// ---------------- pack B (W stack) into MFMA fragment order ----------------
// frag id = k32*8 + nf; within frag: lane*8 + i
// element: B[k32*32 + (lane>>4)*8 + i][nf*16 + (lane&15)]
__global__ void pack_k(const float* __restrict__ Wrel, const float* __restrict__ root,
                       short* __restrict__ Bp, int nk32, int krel){
  int tid = blockIdx.x * 256 + threadIdx.x;
  if (tid >= nk32 * 512) return;
  int lane = tid & 63;
  int nf   = (tid >> 6) & 7;
  int k32  = tid >> 9;
  int col  = nf * 16 + (lane & 15);
  short vals[8];
#pragma unroll
  for (int i = 0; i < 8; ++i){
    int kk = k32 * 32 + ((lane >> 4) << 3) + i;
    float f = (kk < krel) ? Wrel[(size_t)kk * 128 + col]
                          : root[(size_t)(kk - krel) * 128 + col];
    vals[i] = (short)f2bf(f);
  }
  *(bf16x8*)(Bp + (size_t)tid * 8) = *(const bf16x8*)vals;
}

// ---------------- CSR build (relation-major: seg = r*NN + dst) -------------
__global__ void count_k(const int* __restrict__ dst, const int* __restrict__ et,
                        u32* __restrict__ cnt){
  int e = blockIdx.x * 256 + threadIdx.x;
  if (e >= EE) return;
  atomicAdd(&cnt[(size_t)et[e] * NN + dst[e]], 1u);
}

__global__ void scan1_k(const u32* __restrict__ cnt, u32* __restrict__ offs, u32* __restrict__ bsum){
  __shared__ u32 s[512];
  int t = threadIdx.x;                       // 256 threads
  int base = blockIdx.x * 1024 + t * 4;
  u32 loc[4]; u32 sum = 0;
#pragma unroll
  for (int i = 0; i < 4; ++i){ loc[i] = (base + i < NSEG) ? cnt[base + i] : 0u; sum += loc[i]; }
  int pb = 0;
  s[t] = sum; __syncthreads();
  for (int off = 1; off < 256; off <<= 1){
    u32 v = s[pb * 256 + t];
    if (t >= off) v += s[pb * 256 + t - off];
    s[(pb ^ 1) * 256 + t] = v; pb ^= 1; __syncthreads();
  }
  u32 incl = s[pb * 256 + t];
  u32 excl = incl - sum;
  if (t == 255) bsum[blockIdx.x] = incl;
  u32 run = excl;
#pragma unroll
  for (int i = 0; i < 4; ++i){ if (base + i < NSEG) offs[base + i] = run; run += loc[i]; }
}

__global__ void scan2_k(u32* __restrict__ bsum){
  __shared__ u32 s[1024];
  int t = threadIdx.x;                       // 512 threads
  u32 v = (t < NB_SCAN) ? bsum[t] : 0u;
  int pb = 0;
  s[t] = v; __syncthreads();
  for (int off = 1; off < 512; off <<= 1){
    u32 x = s[pb * 512 + t];
    if (t >= off) x += s[pb * 512 + t - off];
    s[(pb ^ 1) * 512 + t] = x; pb ^= 1; __syncthreads();
  }
  u32 incl = s[pb * 512 + t];
  if (t < NB_SCAN) bsum[t] = incl - v;       // exclusive
}

__global__ void scan3_k(u32* __restrict__ offs, const u32* __restrict__ bsum){
  int t = threadIdx.x;
  int base = blockIdx.x * 1024 + t * 4;
  u32 add = bsum[blockIdx.x];
#pragma unroll
  for (int i = 0; i < 4; ++i){ if (base + i < NSEG) offs[base + i] += add; }
  if (blockIdx.x == 0 && t == 0) offs[NSEG] = EE;
}

// fill: reuse cnt as cursor (atomicSub)
__global__ void fill_k(const int* __restrict__ src, const int* __restrict__ dst,
                       const int* __restrict__ et, const u32* __restrict__ offs,
                       u32* __restrict__ cnt, int* __restrict__ elist){
  int e = blockIdx.x * 256 + threadIdx.x;
  if (e >= EE) return;
  int s = et[e] * NN + dst[e];
  u32 p = atomicSub(&cnt[s], 1u);
  elist[offs[s] + p - 1] = src[e];
}

// ------- per-(relation,dst) mean aggregation -> a[R][NN][128] bf16 ----------
// 8-lane group per segment, 32 segments/block; lane owns 32 B of the row.
// 8 independent gather chains per wave, 2-deep edge unroll.
__launch_bounds__(256, 8)
__global__ void agg_k(const u32* __restrict__ offs, const int* __restrict__ elist,
                      const unsigned short* __restrict__ h, unsigned short* __restrict__ a){
  int t = threadIdx.x;
  int g = t >> 3, ll8 = t & 7;
  int seg = blockIdx.x * 32 + g;
  u32 beg = offs[seg], end = offs[seg + 1];
  float s[16];
#pragma unroll
  for (int i = 0; i < 16; ++i) s[i] = 0.f;
  const unsigned short* hb = h + (size_t)ll8 * 16;
  u32 e = beg;
  for (; e + 2 <= end; e += 2){
    int s0 = elist[e], s1 = elist[e + 1];
    const unsigned short* r0 = hb + (size_t)s0 * 128;
    const unsigned short* r1 = hb + (size_t)s1 * 128;
    u32x4 p00 = *(const u32x4*)r0, p01 = *(const u32x4*)(r0 + 8);
    u32x4 p10 = *(const u32x4*)r1, p11 = *(const u32x4*)(r1 + 8);
#pragma unroll
    for (int i = 0; i < 4; ++i){
      s[2*i]     += __uint_as_float(p00[i] << 16)         + __uint_as_float(p10[i] << 16);
      s[2*i+1]   += __uint_as_float(p00[i] & 0xffff0000u) + __uint_as_float(p10[i] & 0xffff0000u);
      s[8+2*i]   += __uint_as_float(p01[i] << 16)         + __uint_as_float(p11[i] << 16);
      s[8+2*i+1] += __uint_as_float(p01[i] & 0xffff0000u) + __uint_as_float(p11[i] & 0xffff0000u);
    }
  }
  if (e < end){
    int s0 = elist[e];
    const unsigned short* r0 = hb + (size_t)s0 * 128;
    u32x4 p00 = *(const u32x4*)r0, p01 = *(const u32x4*)(r0 + 8);
#pragma unroll
    for (int i = 0; i < 4; ++i){
      s[2*i]     += __uint_as_float(p00[i] << 16);
      s[2*i+1]   += __uint_as_float(p00[i] & 0xffff0000u);
      s[8+2*i]   += __uint_as_float(p01[i] << 16);
      s[8+2*i+1] += __uint_as_float(p01[i] & 0xffff0000u);
    }
  }
  u32 deg = end - beg;
  if (deg){
    float inv = 1.f / (float)deg;
#pragma unroll
    for (int i = 0; i < 16; ++i) s[i] *= inv;
  }
  u32x4 o0, o1;
#pragma unroll
  for (int i = 0; i < 4; ++i){
    o0[i] = (u32)f2bf(s[2*i])   | ((u32)f2bf(s[2*i+1])   << 16);
    o1[i] = (u32)f2bf(s[8+2*i]) | ((u32)f2bf(s[8+2*i+1]) << 16);
  }
  unsigned short* ap = a + (size_t)seg * 128 + ll8 * 16;
  *(u32x4*)ap = o0;
  *(u32x4*)(ap + 8) = o1;
}

// ---------------- res projection: resb = bf16(x @ res_w + res_b) ----------
// LDS-free: A-fragments loaded directly from global.
__launch_bounds__(256, 4)
__global__ void resg_k(const unsigned short* __restrict__ xb, const short* __restrict__ Bp,
                       const float* __restrict__ rb, unsigned short* __restrict__ resb){
  const int tid = threadIdx.x;
  const int w = tid >> 6, l = tid & 63;
  const int sub = l >> 4, llr = l & 15;
  const int rowbase = blockIdx.x * 64 + w * 16;
  int vr = rowbase + llr; if (vr > NN - 1) vr = NN - 1;
  f32x4 acc[8] = {};
#pragma unroll
  for (int t = 0; t < 4; ++t){
    bf16x8 af = *(const bf16x8*)(xb + (size_t)vr * 128 + (t * 4 + sub) * 8);
    const short* bb = Bp + (size_t)(t * 8) * 512 + l * 8;
#pragma unroll
    for (int nf = 0; nf < 8; ++nf){
      bf16x8 bq = *(const bf16x8*)(bb + nf * 512);
      acc[nf] = __builtin_amdgcn_mfma_f32_16x16x32_bf16(af, bq, acc[nf], 0, 0, 0);
    }
  }
  const int lr = l >> 4, lc = l & 15;
#pragma unroll
  for (int nf = 0; nf < 8; ++nf){
    int col = nf * 16 + lc;
    float bv = rb[col];
#pragma unroll
    for (int r = 0; r < 4; ++r){
      int row = rowbase + lr * 4 + r;
      if (row < NN) resb[(size_t)row * 128 + col] = f2bf(acc[nf][r] + bv);
    }
  }
}

// -------- MFMA GEMM, LDS-free: out[v,:] = [a_r(v)... | h_v] @ Bp + bias ----
// A-fragments loaded straight from global (per K-step a wave touches 16 rows
// x 128B = whole cache lines, each fetched once). No LDS, no barriers ->
// deep MLP, high occupancy. a is [R][NN][128] (relation-major planes).
// OUTMODE 1: outb = bf16(res + relu(acc+bias)); 2: outf = res + relu(acc+bias)
template<int OUTMODE>
__launch_bounds__(256, 6)
__global__ void gemm_k(const unsigned short* __restrict__ Aa,   // [R][NN][128]
                       const unsigned short* __restrict__ Ah,   // [NN][128]
                       const short* __restrict__ Bp,
                       const float* __restrict__ bias,
                       const unsigned short* __restrict__ resb,
                       float* __restrict__ outf, unsigned short* __restrict__ outb){
  const int tid = threadIdx.x;
  const int w = tid >> 6, l = tid & 63;
  const int sub = l >> 4, llr = l & 15;
  const int rowbase = blockIdx.x * 64 + w * 16;
  int vr = rowbase + llr; if (vr > NN - 1) vr = NN - 1;
  f32x4 acc[8] = {};

#pragma unroll 2
  for (int kt = 0; kt < 16; ++kt){
    const unsigned short* ap = Aa + ((size_t)(kt >> 1) * NN + vr) * 128 + (kt & 1) * 64;
#pragma unroll
    for (int t = 0; t < 2; ++t){
      bf16x8 af = *(const bf16x8*)(ap + (t * 4 + sub) * 8);
      const short* bb = Bp + (size_t)((kt * 2 + t) * 8) * 512 + l * 8;
#pragma unroll
      for (int nf = 0; nf < 8; ++nf){
        bf16x8 bq = *(const bf16x8*)(bb + nf * 512);
        acc[nf] = __builtin_amdgcn_mfma_f32_16x16x32_bf16(af, bq, acc[nf], 0, 0, 0);
      }
    }
  }
#pragma unroll
  for (int kt = 16; kt < 18; ++kt){
    const unsigned short* ap = Ah + (size_t)vr * 128 + (kt - 16) * 64;
#pragma unroll
    for (int t = 0; t < 2; ++t){
      bf16x8 af = *(const bf16x8*)(ap + (t * 4 + sub) * 8);
      const short* bb = Bp + (size_t)((kt * 2 + t) * 8) * 512 + l * 8;
#pragma unroll
      for (int nf = 0; nf < 8; ++nf){
        bf16x8 bq = *(const bf16x8*)(bb + nf * 512);
        acc[nf] = __builtin_amdgcn_mfma_f32_16x16x32_bf16(af, bq, acc[nf], 0, 0, 0);
      }
    }
  }

  const int lr = l >> 4, lc = l & 15;
#pragma unroll
  for (int nf = 0; nf < 8; ++nf){
    int col = nf * 16 + lc;
    float bv = bias[col];
#pragma unroll
    for (int r = 0; r < 4; ++r){
      int row = rowbase + lr * 4 + r;
      if (row < NN){
        float v = acc[nf][r] + bv;
        v = bf2f(resb[(size_t)row * 128 + col]) + fmaxf(v, 0.f);
        if (OUTMODE == 1) outb[(size_t)row * 128 + col] = f2bf(v);
        else              outf[(size_t)row * 128 + col] = v;
      }
    }
  }
}

extern "C" void kernel_launch(void* const* d_in, const int* in_sizes, int n_in,
                              void* d_out, int out_size, void* d_ws, size_t ws_size,
                              hipStream_t stream){
  const float* x  = (const float*)d_in[0];
  const int*   ei = (const int*)d_in[1];
  const int*   et = (const int*)d_in[2];
  const float* W1 = (const float*)d_in[3];
  const float* r1 = (const float*)d_in[4];
  const float* b1 = (const float*)d_in[5];
  const float* W2 = (const float*)d_in[6];
  const float* r2 = (const float*)d_in[7];
  const float* b2 = (const float*)d_in[8];
  const float* W3 = (const float*)d_in[9];
  const float* r3 = (const float*)d_in[10];
  const float* b3 = (const float*)d_in[11];
  const float* rw = (const float*)d_in[12];
  const float* rb = (const float*)d_in[13];
  const int* srcv = ei;
  const int* dstv = ei + EE;

  char* p = (char*)d_ws;
  auto take = [&](size_t b)->char*{ char* q = p; p += (b + 255) & ~(size_t)255; return q; };
  unsigned short* a    = (unsigned short*)take((size_t)NN * 1024 * 2);  // [R][NN][128]
  unsigned short* xb   = (unsigned short*)take((size_t)NN * 128 * 2);
  unsigned short* h1   = (unsigned short*)take((size_t)NN * 128 * 2);
  unsigned short* h2   = (unsigned short*)take((size_t)NN * 128 * 2);
  unsigned short* resb = (unsigned short*)take((size_t)NN * 128 * 2);
  short* Bp1 = (short*)take(36 * 4096 * 2);
  short* Bp2 = (short*)take(36 * 4096 * 2);
  short* Bp3 = (short*)take(36 * 4096 * 2);
  short* BpR = (short*)take(4 * 4096 * 2);
  u32* cnt   = (u32*)take((size_t)NSEG * 4);
  u32* offs  = (u32*)take((size_t)(NSEG + 1) * 4);
  int* elist = (int*)take((size_t)EE * 4);
  u32* bsum  = (u32*)take((size_t)NB_SCAN * 4);

  hipMemsetAsync(cnt, 0, (size_t)NSEG * 4, stream);

  // conversions + weight packing (once)
  cvt_k<<<(NN * 128 / 4 + 255) / 256, 256, 0, stream>>>(x, xb, NN * 128 / 4);
  pack_k<<<(36 * 512 + 255) / 256, 256, 0, stream>>>(W1, r1, Bp1, 36, 1024);
  pack_k<<<(36 * 512 + 255) / 256, 256, 0, stream>>>(W2, r2, Bp2, 36, 1024);
  pack_k<<<(36 * 512 + 255) / 256, 256, 0, stream>>>(W3, r3, Bp3, 36, 1024);
  pack_k<<<(4 * 512 + 255) / 256, 256, 0, stream>>>(nullptr, rw, BpR, 4, 0);

  // CSR over segments (etype*NN + dst), once for all layers
  count_k<<<(EE + 255) / 256, 256, 0, stream>>>(dstv, et, cnt);
  scan1_k<<<NB_SCAN, 256, 0, stream>>>(cnt, offs, bsum);
  scan2_k<<<1, 512, 0, stream>>>(bsum);
  scan3_k<<<NB_SCAN, 256, 0, stream>>>(offs, bsum);
  fill_k<<<(EE + 255) / 256, 256, 0, stream>>>(srcv, dstv, et, offs, cnt, elist);

  const int GB = (NN + 63) / 64;  // 782

  // res = bf16(x @ res_w + res_b)
  resg_k<<<GB, 256, 0, stream>>>(xb, BpR, rb, resb);

  // layer 1
  agg_k<<<NSEG / 32, 256, 0, stream>>>(offs, elist, xb, a);
  gemm_k<1><<<GB, 256, 0, stream>>>(a, xb, Bp1, b1, resb, nullptr, h1);
  // layer 2
  agg_k<<<NSEG / 32, 256, 0, stream>>>(offs, elist, h1, a);
  gemm_k<1><<<GB, 256, 0, stream>>>(a, h1, Bp2, b2, resb, nullptr, h2);
  // layer 3
  agg_k<<<NSEG / 32, 256, 0, stream>>>(offs, elist, h2, a);
  gemm_k<2><<<GB, 256, 0, stream>>>(a, h2, Bp3, b3, resb, (float*)d_out, nullptr);
}

// Round 7
// 405.984 us; speedup vs baseline: 1.2627x; 1.1138x over previous
//
#include <hip/hip_runtime.h>
#include <hip/hip_bf16.h>

#define NN 50000
#define EE 600000
#define RR 8
#define NSEG (NN*RR)                     // 400000
#define NB_SCAN ((NSEG + 1023)/1024)     // 391

typedef unsigned int u32;
typedef __attribute__((ext_vector_type(8))) short bf16x8;
typedef __attribute__((ext_vector_type(4))) float f32x4;
typedef __attribute__((ext_vector_type(4))) u32 u32x4;

// fp32 -> bf16 round-to-nearest-even (finite inputs only)
__device__ inline unsigned short f2bf(float f){
  u32 u = __float_as_uint(f);
  u32 r = (u + 0x7fffu + ((u >> 16) & 1u)) >> 16;
  return (unsigned short)r;
}
__device__ inline float bf2f(unsigned short b){ return __uint_as_float((u32)b << 16); }

// ---------------- conversion: fp32 -> bf16, 4 elems/thread ----------------
__global__ void cvt_k(const float* __restrict__ in, unsigned short* __restrict__ out, int n4){
  int i = blockIdx.x * 256 + threadIdx.x;
  if (i >= n4) return;
  float4 v = ((const float4*)in)[i];
  ushort4 o;
  o.x = f2bf(v.x); o.y = f2bf(v.y); o.z = f2bf(v.z); o.w = f2bf(v.w);
  ((ushort4*)out)[i] = o;
}

// ---------------- pack B (W stack) into MFMA fragment order ----------------
// frag id = k32*8 + nf; within frag: lane*8 + i
// element: B[k32*32 + (lane>>4)*8 + i][nf*16 + (lane&15)]
__global__ void pack_k(const float* __restrict__ Wrel, const float* __restrict__ root,
                       short* __restrict__ Bp, int nk32, int krel){
  int tid = blockIdx.x * 256 + threadIdx.x;
  if (tid >= nk32 * 512) return;
  int lane = tid & 63;
  int nf   = (tid >> 6) & 7;
  int k32  = tid >> 9;
  int col  = nf * 16 + (lane & 15);
  short vals[8];
#pragma unroll
  for (int i = 0; i < 8; ++i){
    int kk = k32 * 32 + ((lane >> 4) << 3) + i;
    float f = (kk < krel) ? Wrel[(size_t)kk * 128 + col]
                          : root[(size_t)(kk - krel) * 128 + col];
    vals[i] = (short)f2bf(f);
  }
  *(bf16x8*)(Bp + (size_t)tid * 8) = *(const bf16x8*)vals;
}

// ---------------- CSR build (relation-major: seg = r*NN + dst) -------------
__global__ void count_k(const int* __restrict__ dst, const int* __restrict__ et,
                        u32* __restrict__ cnt){
  int e = blockIdx.x * 256 + threadIdx.x;
  if (e >= EE) return;
  atomicAdd(&cnt[(size_t)et[e] * NN + dst[e]], 1u);
}

__global__ void scan1_k(const u32* __restrict__ cnt, u32* __restrict__ offs, u32* __restrict__ bsum){
  __shared__ u32 s[512];
  int t = threadIdx.x;                       // 256 threads
  int base = blockIdx.x * 1024 + t * 4;
  u32 loc[4]; u32 sum = 0;
#pragma unroll
  for (int i = 0; i < 4; ++i){ loc[i] = (base + i < NSEG) ? cnt[base + i] : 0u; sum += loc[i]; }
  int pb = 0;
  s[t] = sum; __syncthreads();
  for (int off = 1; off < 256; off <<= 1){
    u32 v = s[pb * 256 + t];
    if (t >= off) v += s[pb * 256 + t - off];
    s[(pb ^ 1) * 256 + t] = v; pb ^= 1; __syncthreads();
  }
  u32 incl = s[pb * 256 + t];
  u32 excl = incl - sum;
  if (t == 255) bsum[blockIdx.x] = incl;
  u32 run = excl;
#pragma unroll
  for (int i = 0; i < 4; ++i){ if (base + i < NSEG) offs[base + i] = run; run += loc[i]; }
}

__global__ void scan2_k(u32* __restrict__ bsum){
  __shared__ u32 s[1024];
  int t = threadIdx.x;                       // 512 threads
  u32 v = (t < NB_SCAN) ? bsum[t] : 0u;
  int pb = 0;
  s[t] = v; __syncthreads();
  for (int off = 1; off < 512; off <<= 1){
    u32 x = s[pb * 512 + t];
    if (t >= off) x += s[pb * 512 + t - off];
    s[(pb ^ 1) * 512 + t] = x; pb ^= 1; __syncthreads();
  }
  u32 incl = s[pb * 512 + t];
  if (t < NB_SCAN) bsum[t] = incl - v;       // exclusive
}

__global__ void scan3_k(u32* __restrict__ offs, const u32* __restrict__ bsum){
  int t = threadIdx.x;
  int base = blockIdx.x * 1024 + t * 4;
  u32 add = bsum[blockIdx.x];
#pragma unroll
  for (int i = 0; i < 4; ++i){ if (base + i < NSEG) offs[base + i] += add; }
  if (blockIdx.x == 0 && t == 0) offs[NSEG] = EE;
}

// fill: reuse cnt as cursor (atomicSub)
__global__ void fill_k(const int* __restrict__ src, const int* __restrict__ dst,
                       const int* __restrict__ et, const u32* __restrict__ offs,
                       u32* __restrict__ cnt, int* __restrict__ elist){
  int e = blockIdx.x * 256 + threadIdx.x;
  if (e >= EE) return;
  int s = et[e] * NN + dst[e];
  u32 p = atomicSub(&cnt[s], 1u);
  elist[offs[s] + p - 1] = src[e];
}

// ------- per-(relation,dst) mean aggregation -> a[R][NN][128] bf16 ----------
// 8-lane group per segment, 32 segments/block; lane owns 32 B of the row.
// 8 independent gather chains per wave, 2-deep edge unroll.
__launch_bounds__(256, 8)
__global__ void agg_k(const u32* __restrict__ offs, const int* __restrict__ elist,
                      const unsigned short* __restrict__ h, unsigned short* __restrict__ a){
  int t = threadIdx.x;
  int g = t >> 3, ll8 = t & 7;
  int seg = blockIdx.x * 32 + g;
  u32 beg = offs[seg], end = offs[seg + 1];
  float s[16];
#pragma unroll
  for (int i = 0; i < 16; ++i) s[i] = 0.f;
  const unsigned short* hb = h + (size_t)ll8 * 16;
  u32 e = beg;
  for (; e + 2 <= end; e += 2){
    int s0 = elist[e], s1 = elist[e + 1];
    const unsigned short* r0 = hb + (size_t)s0 * 128;
    const unsigned short* r1 = hb + (size_t)s1 * 128;
    u32x4 p00 = *(const u32x4*)r0, p01 = *(const u32x4*)(r0 + 8);
    u32x4 p10 = *(const u32x4*)r1, p11 = *(const u32x4*)(r1 + 8);
#pragma unroll
    for (int i = 0; i < 4; ++i){
      s[2*i]     += __uint_as_float(p00[i] << 16)         + __uint_as_float(p10[i] << 16);
      s[2*i+1]   += __uint_as_float(p00[i] & 0xffff0000u) + __uint_as_float(p10[i] & 0xffff0000u);
      s[8+2*i]   += __uint_as_float(p01[i] << 16)         + __uint_as_float(p11[i] << 16);
      s[8+2*i+1] += __uint_as_float(p01[i] & 0xffff0000u) + __uint_as_float(p11[i] & 0xffff0000u);
    }
  }
  if (e < end){
    int s0 = elist[e];
    const unsigned short* r0 = hb + (size_t)s0 * 128;
    u32x4 p00 = *(const u32x4*)r0, p01 = *(const u32x4*)(r0 + 8);
#pragma unroll
    for (int i = 0; i < 4; ++i){
      s[2*i]     += __uint_as_float(p00[i] << 16);
      s[2*i+1]   += __uint_as_float(p00[i] & 0xffff0000u);
      s[8+2*i]   += __uint_as_float(p01[i] << 16);
      s[8+2*i+1] += __uint_as_float(p01[i] & 0xffff0000u);
    }
  }
  u32 deg = end - beg;
  if (deg){
    float inv = 1.f / (float)deg;
#pragma unroll
    for (int i = 0; i < 16; ++i) s[i] *= inv;
  }
  u32x4 o0, o1;
#pragma unroll
  for (int i = 0; i < 4; ++i){
    o0[i] = (u32)f2bf(s[2*i])   | ((u32)f2bf(s[2*i+1])   << 16);
    o1[i] = (u32)f2bf(s[8+2*i]) | ((u32)f2bf(s[8+2*i+1]) << 16);
  }
  unsigned short* ap = a + (size_t)seg * 128 + ll8 * 16;
  *(u32x4*)ap = o0;
  *(u32x4*)(ap + 8) = o1;
}

// ---------------- res projection: resb = bf16(x @ res_w + res_b) ----------
// LDS-free: A-fragments loaded directly from global.
__launch_bounds__(256, 4)
__global__ void resg_k(const unsigned short* __restrict__ xb, const short* __restrict__ Bp,
                       const float* __restrict__ rb, unsigned short* __restrict__ resb){
  const int tid = threadIdx.x;
  const int w = tid >> 6, l = tid & 63;
  const int sub = l >> 4, llr = l & 15;
  const int rowbase = blockIdx.x * 64 + w * 16;
  int vr = rowbase + llr; if (vr > NN - 1) vr = NN - 1;
  f32x4 acc[8] = {};
#pragma unroll
  for (int t = 0; t < 4; ++t){
    bf16x8 af = *(const bf16x8*)(xb + (size_t)vr * 128 + (t * 4 + sub) * 8);
    const short* bb = Bp + (size_t)(t * 8) * 512 + l * 8;
#pragma unroll
    for (int nf = 0; nf < 8; ++nf){
      bf16x8 bq = *(const bf16x8*)(bb + nf * 512);
      acc[nf] = __builtin_amdgcn_mfma_f32_16x16x32_bf16(af, bq, acc[nf], 0, 0, 0);
    }
  }
  const int lr = l >> 4, lc = l & 15;
#pragma unroll
  for (int nf = 0; nf < 8; ++nf){
    int col = nf * 16 + lc;
    float bv = rb[col];
#pragma unroll
    for (int r = 0; r < 4; ++r){
      int row = rowbase + lr * 4 + r;
      if (row < NN) resb[(size_t)row * 128 + col] = f2bf(acc[nf][r] + bv);
    }
  }
}

// -------- MFMA GEMM, LDS-free, 32 rows/wave ---------------------------------
// out[v,:] = [a_r(v)... | h_v] @ Bp + bias, then res+relu epilogue.
// 128-thread blocks (2 waves); each wave owns 32 rows (2 16-row A-frags).
// Per (kt,t) step: 10 loads (2 af + 8 bq) feed 16 MFMAs — 2x the work per
// B-byte vs 16-row waves, halving L2 B-traffic and doubling ILP.
// OUTMODE 1: outb = bf16(res + relu(acc+bias)); 2: outf = res + relu(acc+bias)
template<int OUTMODE>
__launch_bounds__(128, 4)
__global__ void gemm_k(const unsigned short* __restrict__ Aa,   // [R][NN][128]
                       const unsigned short* __restrict__ Ah,   // [NN][128]
                       const short* __restrict__ Bp,
                       const float* __restrict__ bias,
                       const unsigned short* __restrict__ resb,
                       float* __restrict__ outf, unsigned short* __restrict__ outb){
  const int tid = threadIdx.x;
  const int w = tid >> 6, l = tid & 63;
  const int sub = l >> 4, llr = l & 15;
  const int rowbase = blockIdx.x * 64 + w * 32;
  int vr0 = rowbase + llr;      if (vr0 > NN - 1) vr0 = NN - 1;
  int vr1 = rowbase + 16 + llr; if (vr1 > NN - 1) vr1 = NN - 1;
  f32x4 acc[2][8] = {};

#pragma unroll 4
  for (int kt = 0; kt < 16; ++kt){
    const unsigned short* ap0 = Aa + ((size_t)(kt >> 1) * NN + vr0) * 128 + (kt & 1) * 64;
    const unsigned short* ap1 = Aa + ((size_t)(kt >> 1) * NN + vr1) * 128 + (kt & 1) * 64;
#pragma unroll
    for (int t = 0; t < 2; ++t){
      bf16x8 af0 = *(const bf16x8*)(ap0 + (t * 4 + sub) * 8);
      bf16x8 af1 = *(const bf16x8*)(ap1 + (t * 4 + sub) * 8);
      const short* bb = Bp + (size_t)((kt * 2 + t) * 8) * 512 + l * 8;
#pragma unroll
      for (int nf = 0; nf < 8; ++nf){
        bf16x8 bq = *(const bf16x8*)(bb + nf * 512);
        acc[0][nf] = __builtin_amdgcn_mfma_f32_16x16x32_bf16(af0, bq, acc[0][nf], 0, 0, 0);
        acc[1][nf] = __builtin_amdgcn_mfma_f32_16x16x32_bf16(af1, bq, acc[1][nf], 0, 0, 0);
      }
    }
  }
#pragma unroll
  for (int kt = 16; kt < 18; ++kt){
    const unsigned short* ap0 = Ah + (size_t)vr0 * 128 + (kt - 16) * 64;
    const unsigned short* ap1 = Ah + (size_t)vr1 * 128 + (kt - 16) * 64;
#pragma unroll
    for (int t = 0; t < 2; ++t){
      bf16x8 af0 = *(const bf16x8*)(ap0 + (t * 4 + sub) * 8);
      bf16x8 af1 = *(const bf16x8*)(ap1 + (t * 4 + sub) * 8);
      const short* bb = Bp + (size_t)((kt * 2 + t) * 8) * 512 + l * 8;
#pragma unroll
      for (int nf = 0; nf < 8; ++nf){
        bf16x8 bq = *(const bf16x8*)(bb + nf * 512);
        acc[0][nf] = __builtin_amdgcn_mfma_f32_16x16x32_bf16(af0, bq, acc[0][nf], 0, 0, 0);
        acc[1][nf] = __builtin_amdgcn_mfma_f32_16x16x32_bf16(af1, bq, acc[1][nf], 0, 0, 0);
      }
    }
  }

  const int lr = l >> 4, lc = l & 15;
#pragma unroll
  for (int mf = 0; mf < 2; ++mf){
#pragma unroll
    for (int nf = 0; nf < 8; ++nf){
      int col = nf * 16 + lc;
      float bv = bias[col];
#pragma unroll
      for (int r = 0; r < 4; ++r){
        int row = rowbase + mf * 16 + lr * 4 + r;
        if (row < NN){
          float v = acc[mf][nf][r] + bv;
          v = bf2f(resb[(size_t)row * 128 + col]) + fmaxf(v, 0.f);
          if (OUTMODE == 1) outb[(size_t)row * 128 + col] = f2bf(v);
          else              outf[(size_t)row * 128 + col] = v;
        }
      }
    }
  }
}

extern "C" void kernel_launch(void* const* d_in, const int* in_sizes, int n_in,
                              void* d_out, int out_size, void* d_ws, size_t ws_size,
                              hipStream_t stream){
  const float* x  = (const float*)d_in[0];
  const int*   ei = (const int*)d_in[1];
  const int*   et = (const int*)d_in[2];
  const float* W1 = (const float*)d_in[3];
  const float* r1 = (const float*)d_in[4];
  const float* b1 = (const float*)d_in[5];
  const float* W2 = (const float*)d_in[6];
  const float* r2 = (const float*)d_in[7];
  const float* b2 = (const float*)d_in[8];
  const float* W3 = (const float*)d_in[9];
  const float* r3 = (const float*)d_in[10];
  const float* b3 = (const float*)d_in[11];
  const float* rw = (const float*)d_in[12];
  const float* rb = (const float*)d_in[13];
  const int* srcv = ei;
  const int* dstv = ei + EE;

  char* p = (char*)d_ws;
  auto take = [&](size_t b)->char*{ char* q = p; p += (b + 255) & ~(size_t)255; return q; };
  unsigned short* a    = (unsigned short*)take((size_t)NN * 1024 * 2);  // [R][NN][128]
  unsigned short* xb   = (unsigned short*)take((size_t)NN * 128 * 2);
  unsigned short* h1   = (unsigned short*)take((size_t)NN * 128 * 2);
  unsigned short* h2   = (unsigned short*)take((size_t)NN * 128 * 2);
  unsigned short* resb = (unsigned short*)take((size_t)NN * 128 * 2);
  short* Bp1 = (short*)take(36 * 4096 * 2);
  short* Bp2 = (short*)take(36 * 4096 * 2);
  short* Bp3 = (short*)take(36 * 4096 * 2);
  short* BpR = (short*)take(4 * 4096 * 2);
  u32* cnt   = (u32*)take((size_t)NSEG * 4);
  u32* offs  = (u32*)take((size_t)(NSEG + 1) * 4);
  int* elist = (int*)take((size_t)EE * 4);
  u32* bsum  = (u32*)take((size_t)NB_SCAN * 4);

  hipMemsetAsync(cnt, 0, (size_t)NSEG * 4, stream);

  // conversions + weight packing (once)
  cvt_k<<<(NN * 128 / 4 + 255) / 256, 256, 0, stream>>>(x, xb, NN * 128 / 4);
  pack_k<<<(36 * 512 + 255) / 256, 256, 0, stream>>>(W1, r1, Bp1, 36, 1024);
  pack_k<<<(36 * 512 + 255) / 256, 256, 0, stream>>>(W2, r2, Bp2, 36, 1024);
  pack_k<<<(36 * 512 + 255) / 256, 256, 0, stream>>>(W3, r3, Bp3, 36, 1024);
  pack_k<<<(4 * 512 + 255) / 256, 256, 0, stream>>>(nullptr, rw, BpR, 4, 0);

  // CSR over segments (etype*NN + dst), once for all layers
  count_k<<<(EE + 255) / 256, 256, 0, stream>>>(dstv, et, cnt);
  scan1_k<<<NB_SCAN, 256, 0, stream>>>(cnt, offs, bsum);
  scan2_k<<<1, 512, 0, stream>>>(bsum);
  scan3_k<<<NB_SCAN, 256, 0, stream>>>(offs, bsum);
  fill_k<<<(EE + 255) / 256, 256, 0, stream>>>(srcv, dstv, et, offs, cnt, elist);

  const int GB = (NN + 63) / 64;  // 782

  // res = bf16(x @ res_w + res_b)
  resg_k<<<GB, 256, 0, stream>>>(xb, BpR, rb, resb);

  // layer 1
  agg_k<<<NSEG / 32, 256, 0, stream>>>(offs, elist, xb, a);
  gemm_k<1><<<GB, 128, 0, stream>>>(a, xb, Bp1, b1, resb, nullptr, h1);
  // layer 2
  agg_k<<<NSEG / 32, 256, 0, stream>>>(offs, elist, h1, a);
  gemm_k<1><<<GB, 128, 0, stream>>>(a, h1, Bp2, b2, resb, nullptr, h2);
  // layer 3
  agg_k<<<NSEG / 32, 256, 0, stream>>>(offs, elist, h2, a);
  gemm_k<2><<<GB, 128, 0, stream>>>(a, h2, Bp3, b3, resb, (float*)d_out, nullptr);
}

// Round 8
// 396.425 us; speedup vs baseline: 1.2932x; 1.0241x over previous
//
#include <hip/hip_runtime.h>
#include <hip/hip_bf16.h>

#define NN 50000
#define EE 600000
#define RR 8
#define NSEG (NN*RR)                     // 400000
#define NB_SCAN ((NSEG + 1023)/1024)     // 391
#define PF 6                             // A-prefetch depth (kt steps)

typedef unsigned int u32;
typedef __attribute__((ext_vector_type(8))) short bf16x8;
typedef __attribute__((ext_vector_type(4))) float f32x4;
typedef __attribute__((ext_vector_type(4))) u32 u32x4;

// fp32 -> bf16 round-to-nearest-even (finite inputs only)
__device__ inline unsigned short f2bf(float f){
  u32 u = __float_as_uint(f);
  u32 r = (u + 0x7fffu + ((u >> 16) & 1u)) >> 16;
  return (unsigned short)r;
}
__device__ inline float bf2f(unsigned short b){ return __uint_as_float((u32)b << 16); }

// ---------------- conversion: fp32 -> bf16, 4 elems/thread ----------------
__global__ void cvt_k(const float* __restrict__ in, unsigned short* __restrict__ out, int n4){
  int i = blockIdx.x * 256 + threadIdx.x;
  if (i >= n4) return;
  float4 v = ((const float4*)in)[i];
  ushort4 o;
  o.x = f2bf(v.x); o.y = f2bf(v.y); o.z = f2bf(v.z); o.w = f2bf(v.w);
  ((ushort4*)out)[i] = o;
}

// ---------------- pack B (W stack) into MFMA fragment order ----------------
// frag id = k32*8 + nf; within frag: lane*8 + i
// element: B[k32*32 + (lane>>4)*8 + i][nf*16 + (lane&15)]
__global__ void pack_k(const float* __restrict__ Wrel, const float* __restrict__ root,
                       short* __restrict__ Bp, int nk32, int krel){
  int tid = blockIdx.x * 256 + threadIdx.x;
  if (tid >= nk32 * 512) return;
  int lane = tid & 63;
  int nf   = (tid >> 6) & 7;
  int k32  = tid >> 9;
  int col  = nf * 16 + (lane & 15);
  short vals[8];
#pragma unroll
  for (int i = 0; i < 8; ++i){
    int kk = k32 * 32 + ((lane >> 4) << 3) + i;
    float f = (kk < krel) ? Wrel[(size_t)kk * 128 + col]
                          : root[(size_t)(kk - krel) * 128 + col];
    vals[i] = (short)f2bf(f);
  }
  *(bf16x8*)(Bp + (size_t)tid * 8) = *(const bf16x8*)vals;
}

// ---------------- CSR build (relation-major: seg = r*NN + dst) -------------
__global__ void count_k(const int* __restrict__ dst, const int* __restrict__ et,
                        u32* __restrict__ cnt){
  int e = blockIdx.x * 256 + threadIdx.x;
  if (e >= EE) return;
  atomicAdd(&cnt[(size_t)et[e] * NN + dst[e]], 1u);
}

__global__ void scan1_k(const u32* __restrict__ cnt, u32* __restrict__ offs, u32* __restrict__ bsum){
  __shared__ u32 s[512];
  int t = threadIdx.x;                       // 256 threads
  int base = blockIdx.x * 1024 + t * 4;
  u32 loc[4]; u32 sum = 0;
#pragma unroll
  for (int i = 0; i < 4; ++i){ loc[i] = (base + i < NSEG) ? cnt[base + i] : 0u; sum += loc[i]; }
  int pb = 0;
  s[t] = sum; __syncthreads();
  for (int off = 1; off < 256; off <<= 1){
    u32 v = s[pb * 256 + t];
    if (t >= off) v += s[pb * 256 + t - off];
    s[(pb ^ 1) * 256 + t] = v; pb ^= 1; __syncthreads();
  }
  u32 incl = s[pb * 256 + t];
  u32 excl = incl - sum;
  if (t == 255) bsum[blockIdx.x] = incl;
  u32 run = excl;
#pragma unroll
  for (int i = 0; i < 4; ++i){ if (base + i < NSEG) offs[base + i] = run; run += loc[i]; }
}

__global__ void scan2_k(u32* __restrict__ bsum){
  __shared__ u32 s[1024];
  int t = threadIdx.x;                       // 512 threads
  u32 v = (t < NB_SCAN) ? bsum[t] : 0u;
  int pb = 0;
  s[t] = v; __syncthreads();
  for (int off = 1; off < 512; off <<= 1){
    u32 x = s[pb * 512 + t];
    if (t >= off) x += s[pb * 512 + t - off];
    s[(pb ^ 1) * 512 + t] = x; pb ^= 1; __syncthreads();
  }
  u32 incl = s[pb * 512 + t];
  if (t < NB_SCAN) bsum[t] = incl - v;       // exclusive
}

__global__ void scan3_k(u32* __restrict__ offs, const u32* __restrict__ bsum){
  int t = threadIdx.x;
  int base = blockIdx.x * 1024 + t * 4;
  u32 add = bsum[blockIdx.x];
#pragma unroll
  for (int i = 0; i < 4; ++i){ if (base + i < NSEG) offs[base + i] += add; }
  if (blockIdx.x == 0 && t == 0) offs[NSEG] = EE;
}

// fill: reuse cnt as cursor (atomicSub)
__global__ void fill_k(const int* __restrict__ src, const int* __restrict__ dst,
                       const int* __restrict__ et, const u32* __restrict__ offs,
                       u32* __restrict__ cnt, int* __restrict__ elist){
  int e = blockIdx.x * 256 + threadIdx.x;
  if (e >= EE) return;
  int s = et[e] * NN + dst[e];
  u32 p = atomicSub(&cnt[s], 1u);
  elist[offs[s] + p - 1] = src[e];
}

// ------- per-(relation,dst) mean aggregation -> a[R][NN][128] bf16 ----------
// 8-lane group per segment, 32 segments/block; lane owns 32 B of the row.
// 8 independent gather chains per wave, 2-deep edge unroll.
__launch_bounds__(256, 8)
__global__ void agg_k(const u32* __restrict__ offs, const int* __restrict__ elist,
                      const unsigned short* __restrict__ h, unsigned short* __restrict__ a){
  int t = threadIdx.x;
  int g = t >> 3, ll8 = t & 7;
  int seg = blockIdx.x * 32 + g;
  u32 beg = offs[seg], end = offs[seg + 1];
  float s[16];
#pragma unroll
  for (int i = 0; i < 16; ++i) s[i] = 0.f;
  const unsigned short* hb = h + (size_t)ll8 * 16;
  u32 e = beg;
  for (; e + 2 <= end; e += 2){
    int s0 = elist[e], s1 = elist[e + 1];
    const unsigned short* r0 = hb + (size_t)s0 * 128;
    const unsigned short* r1 = hb + (size_t)s1 * 128;
    u32x4 p00 = *(const u32x4*)r0, p01 = *(const u32x4*)(r0 + 8);
    u32x4 p10 = *(const u32x4*)r1, p11 = *(const u32x4*)(r1 + 8);
#pragma unroll
    for (int i = 0; i < 4; ++i){
      s[2*i]     += __uint_as_float(p00[i] << 16)         + __uint_as_float(p10[i] << 16);
      s[2*i+1]   += __uint_as_float(p00[i] & 0xffff0000u) + __uint_as_float(p10[i] & 0xffff0000u);
      s[8+2*i]   += __uint_as_float(p01[i] << 16)         + __uint_as_float(p11[i] << 16);
      s[8+2*i+1] += __uint_as_float(p01[i] & 0xffff0000u) + __uint_as_float(p11[i] & 0xffff0000u);
    }
  }
  if (e < end){
    int s0 = elist[e];
    const unsigned short* r0 = hb + (size_t)s0 * 128;
    u32x4 p00 = *(const u32x4*)r0, p01 = *(const u32x4*)(r0 + 8);
#pragma unroll
    for (int i = 0; i < 4; ++i){
      s[2*i]     += __uint_as_float(p00[i] << 16);
      s[2*i+1]   += __uint_as_float(p00[i] & 0xffff0000u);
      s[8+2*i]   += __uint_as_float(p01[i] << 16);
      s[8+2*i+1] += __uint_as_float(p01[i] & 0xffff0000u);
    }
  }
  u32 deg = end - beg;
  if (deg){
    float inv = 1.f / (float)deg;
#pragma unroll
    for (int i = 0; i < 16; ++i) s[i] *= inv;
  }
  u32x4 o0, o1;
#pragma unroll
  for (int i = 0; i < 4; ++i){
    o0[i] = (u32)f2bf(s[2*i])   | ((u32)f2bf(s[2*i+1])   << 16);
    o1[i] = (u32)f2bf(s[8+2*i]) | ((u32)f2bf(s[8+2*i+1]) << 16);
  }
  unsigned short* ap = a + (size_t)seg * 128 + ll8 * 16;
  *(u32x4*)ap = o0;
  *(u32x4*)(ap + 8) = o1;
}

// ---------------- res projection: resb = bf16(x @ res_w + res_b) ----------
__launch_bounds__(256, 4)
__global__ void resg_k(const unsigned short* __restrict__ xb, const short* __restrict__ Bp,
                       const float* __restrict__ rb, unsigned short* __restrict__ resb){
  const int tid = threadIdx.x;
  const int w = tid >> 6, l = tid & 63;
  const int sub = l >> 4, llr = l & 15;
  const int rowbase = blockIdx.x * 64 + w * 16;
  int vr = rowbase + llr; if (vr > NN - 1) vr = NN - 1;
  f32x4 acc[8] = {};
#pragma unroll
  for (int t = 0; t < 4; ++t){
    bf16x8 af = *(const bf16x8*)(xb + (size_t)vr * 128 + (t * 4 + sub) * 8);
    const short* bb = Bp + (size_t)(t * 8) * 512 + l * 8;
#pragma unroll
    for (int nf = 0; nf < 8; ++nf){
      bf16x8 bq = *(const bf16x8*)(bb + nf * 512);
      acc[nf] = __builtin_amdgcn_mfma_f32_16x16x32_bf16(af, bq, acc[nf], 0, 0, 0);
    }
  }
  const int lr = l >> 4, lc = l & 15;
#pragma unroll
  for (int nf = 0; nf < 8; ++nf){
    int col = nf * 16 + lc;
    float bv = rb[col];
#pragma unroll
    for (int r = 0; r < 4; ++r){
      int row = rowbase + lr * 4 + r;
      if (row < NN) resb[(size_t)row * 128 + col] = f2bf(acc[nf][r] + bv);
    }
  }
}

// -------- MFMA GEMM, LDS-free, 32 rows/wave, PF-deep A register pipeline ----
// out[v,:] = [a_r(v)... | h_v] @ Bp + bias, then res+relu epilogue.
// Fully-unrolled K loop; af ring indices are compile-time (rule #20).
// ~12 A-loads in flight per wave hide HBM latency; B-loads are L1/L2-hot.
template<int OUTMODE>
__launch_bounds__(128, 2)
__global__ void gemm_k(const unsigned short* __restrict__ Aa,   // [R][NN][128]
                       const unsigned short* __restrict__ Ah,   // [NN][128]
                       const short* __restrict__ Bp,
                       const float* __restrict__ bias,
                       const unsigned short* __restrict__ resb,
                       float* __restrict__ outf, unsigned short* __restrict__ outb){
  const int tid = threadIdx.x;
  const int w = tid >> 6, l = tid & 63;
  const int sub = l >> 4, llr = l & 15;
  const int rowbase = blockIdx.x * 64 + w * 32;
  int vr0 = rowbase + llr;      if (vr0 > NN - 1) vr0 = NN - 1;
  int vr1 = rowbase + 16 + llr; if (vr1 > NN - 1) vr1 = NN - 1;
  f32x4 acc[2][8] = {};
  bf16x8 af[PF][2][2];                       // [slot][t][half] — static idx only

  const unsigned short* a0 = Aa + (size_t)vr0 * 128;
  const unsigned short* a1 = Aa + (size_t)vr1 * 128;
  const unsigned short* h0 = Ah + (size_t)vr0 * 128;
  const unsigned short* h1 = Ah + (size_t)vr1 * 128;
  const size_t plane = (size_t)NN * 128;

#define ALOAD(slot, kt) do{ \
    if ((kt) < 16){ \
      const unsigned short* p0_ = a0 + (size_t)((kt) >> 1) * plane + ((kt) & 1) * 64; \
      const unsigned short* p1_ = a1 + (size_t)((kt) >> 1) * plane + ((kt) & 1) * 64; \
      af[slot][0][0] = *(const bf16x8*)(p0_ + (0 * 4 + sub) * 8); \
      af[slot][0][1] = *(const bf16x8*)(p1_ + (0 * 4 + sub) * 8); \
      af[slot][1][0] = *(const bf16x8*)(p0_ + (1 * 4 + sub) * 8); \
      af[slot][1][1] = *(const bf16x8*)(p1_ + (1 * 4 + sub) * 8); \
    } else { \
      const unsigned short* p0_ = h0 + ((kt) - 16) * 64; \
      const unsigned short* p1_ = h1 + ((kt) - 16) * 64; \
      af[slot][0][0] = *(const bf16x8*)(p0_ + (0 * 4 + sub) * 8); \
      af[slot][0][1] = *(const bf16x8*)(p1_ + (0 * 4 + sub) * 8); \
      af[slot][1][0] = *(const bf16x8*)(p0_ + (1 * 4 + sub) * 8); \
      af[slot][1][1] = *(const bf16x8*)(p1_ + (1 * 4 + sub) * 8); \
    } \
  }while(0)

#pragma unroll
  for (int k = 0; k < PF; ++k) ALOAD(k, k);

#pragma unroll
  for (int kt = 0; kt < 18; ++kt){
    const int s = kt % PF;
#pragma unroll
    for (int t = 0; t < 2; ++t){
      const short* bb = Bp + (size_t)((kt * 2 + t) * 8) * 512 + l * 8;
#pragma unroll
      for (int nf = 0; nf < 8; ++nf){
        bf16x8 bq = *(const bf16x8*)(bb + nf * 512);
        acc[0][nf] = __builtin_amdgcn_mfma_f32_16x16x32_bf16(af[s][t][0], bq, acc[0][nf], 0, 0, 0);
        acc[1][nf] = __builtin_amdgcn_mfma_f32_16x16x32_bf16(af[s][t][1], bq, acc[1][nf], 0, 0, 0);
      }
    }
    if (kt + PF < 18) ALOAD(s, kt + PF);
  }
#undef ALOAD

  const int lr = l >> 4, lc = l & 15;
#pragma unroll
  for (int mf = 0; mf < 2; ++mf){
#pragma unroll
    for (int nf = 0; nf < 8; ++nf){
      int col = nf * 16 + lc;
      float bv = bias[col];
#pragma unroll
      for (int r = 0; r < 4; ++r){
        int row = rowbase + mf * 16 + lr * 4 + r;
        if (row < NN){
          float v = acc[mf][nf][r] + bv;
          v = bf2f(resb[(size_t)row * 128 + col]) + fmaxf(v, 0.f);
          if (OUTMODE == 1) outb[(size_t)row * 128 + col] = f2bf(v);
          else              outf[(size_t)row * 128 + col] = v;
        }
      }
    }
  }
}

extern "C" void kernel_launch(void* const* d_in, const int* in_sizes, int n_in,
                              void* d_out, int out_size, void* d_ws, size_t ws_size,
                              hipStream_t stream){
  const float* x  = (const float*)d_in[0];
  const int*   ei = (const int*)d_in[1];
  const int*   et = (const int*)d_in[2];
  const float* W1 = (const float*)d_in[3];
  const float* r1 = (const float*)d_in[4];
  const float* b1 = (const float*)d_in[5];
  const float* W2 = (const float*)d_in[6];
  const float* r2 = (const float*)d_in[7];
  const float* b2 = (const float*)d_in[8];
  const float* W3 = (const float*)d_in[9];
  const float* r3 = (const float*)d_in[10];
  const float* b3 = (const float*)d_in[11];
  const float* rw = (const float*)d_in[12];
  const float* rb = (const float*)d_in[13];
  const int* srcv = ei;
  const int* dstv = ei + EE;

  char* p = (char*)d_ws;
  auto take = [&](size_t b)->char*{ char* q = p; p += (b + 255) & ~(size_t)255; return q; };
  unsigned short* a    = (unsigned short*)take((size_t)NN * 1024 * 2);  // [R][NN][128]
  unsigned short* xb   = (unsigned short*)take((size_t)NN * 128 * 2);
  unsigned short* h1   = (unsigned short*)take((size_t)NN * 128 * 2);
  unsigned short* h2   = (unsigned short*)take((size_t)NN * 128 * 2);
  unsigned short* resb = (unsigned short*)take((size_t)NN * 128 * 2);
  short* Bp1 = (short*)take(36 * 4096 * 2);
  short* Bp2 = (short*)take(36 * 4096 * 2);
  short* Bp3 = (short*)take(36 * 4096 * 2);
  short* BpR = (short*)take(4 * 4096 * 2);
  u32* cnt   = (u32*)take((size_t)NSEG * 4);
  u32* offs  = (u32*)take((size_t)(NSEG + 1) * 4);
  int* elist = (int*)take((size_t)EE * 4);
  u32* bsum  = (u32*)take((size_t)NB_SCAN * 4);

  hipMemsetAsync(cnt, 0, (size_t)NSEG * 4, stream);

  // conversions + weight packing (once)
  cvt_k<<<(NN * 128 / 4 + 255) / 256, 256, 0, stream>>>(x, xb, NN * 128 / 4);
  pack_k<<<(36 * 512 + 255) / 256, 256, 0, stream>>>(W1, r1, Bp1, 36, 1024);
  pack_k<<<(36 * 512 + 255) / 256, 256, 0, stream>>>(W2, r2, Bp2, 36, 1024);
  pack_k<<<(36 * 512 + 255) / 256, 256, 0, stream>>>(W3, r3, Bp3, 36, 1024);
  pack_k<<<(4 * 512 + 255) / 256, 256, 0, stream>>>(nullptr, rw, BpR, 4, 0);

  // CSR over segments (etype*NN + dst), once for all layers
  count_k<<<(EE + 255) / 256, 256, 0, stream>>>(dstv, et, cnt);
  scan1_k<<<NB_SCAN, 256, 0, stream>>>(cnt, offs, bsum);
  scan2_k<<<1, 512, 0, stream>>>(bsum);
  scan3_k<<<NB_SCAN, 256, 0, stream>>>(offs, bsum);
  fill_k<<<(EE + 255) / 256, 256, 0, stream>>>(srcv, dstv, et, offs, cnt, elist);

  const int GB = (NN + 63) / 64;  // 782

  // res = bf16(x @ res_w + res_b)
  resg_k<<<GB, 256, 0, stream>>>(xb, BpR, rb, resb);

  // layer 1
  agg_k<<<NSEG / 32, 256, 0, stream>>>(offs, elist, xb, a);
  gemm_k<1><<<GB, 128, 0, stream>>>(a, xb, Bp1, b1, resb, nullptr, h1);
  // layer 2
  agg_k<<<NSEG / 32, 256, 0, stream>>>(offs, elist, h1, a);
  gemm_k<1><<<GB, 128, 0, stream>>>(a, h1, Bp2, b2, resb, nullptr, h2);
  // layer 3
  agg_k<<<NSEG / 32, 256, 0, stream>>>(offs, elist, h2, a);
  gemm_k<2><<<GB, 128, 0, stream>>>(a, h2, Bp3, b3, resb, (float*)d_out, nullptr);
}

// Round 9
// 347.374 us; speedup vs baseline: 1.4758x; 1.1412x over previous
//
#include <hip/hip_runtime.h>
#include <hip/hip_bf16.h>

#define NN 50000
#define EE 600000
#define RR 8
#define NSEG (NN*RR)                     // 400000
#define NB_SCAN ((NSEG + 1023)/1024)     // 391

typedef unsigned int u32;
typedef __attribute__((ext_vector_type(8))) short bf16x8;
typedef __attribute__((ext_vector_type(4))) float f32x4;
typedef __attribute__((ext_vector_type(4))) u32 u32x4;

// fp32 -> bf16 round-to-nearest-even (finite inputs only)
__device__ inline unsigned short f2bf(float f){
  u32 u = __float_as_uint(f);
  u32 r = (u + 0x7fffu + ((u >> 16) & 1u)) >> 16;
  return (unsigned short)r;
}
__device__ inline float bf2f(unsigned short b){ return __uint_as_float((u32)b << 16); }

#define GLD16(g, l)  __builtin_amdgcn_global_load_lds( \
    (const __attribute__((address_space(1))) void*)(g), \
    (__attribute__((address_space(3))) void*)(l), 16, 0, 0)

// ---------------- conversion: fp32 -> bf16, 4 elems/thread ----------------
__global__ void cvt_k(const float* __restrict__ in, unsigned short* __restrict__ out, int n4){
  int i = blockIdx.x * 256 + threadIdx.x;
  if (i >= n4) return;
  float4 v = ((const float4*)in)[i];
  ushort4 o;
  o.x = f2bf(v.x); o.y = f2bf(v.y); o.z = f2bf(v.z); o.w = f2bf(v.w);
  ((ushort4*)out)[i] = o;
}

// ---------------- pack B (W stack) into MFMA fragment order ----------------
// frag id = k32*8 + nf; within frag: lane*8 + i
// element: B[k32*32 + (lane>>4)*8 + i][nf*16 + (lane&15)]
__global__ void pack_k(const float* __restrict__ Wrel, const float* __restrict__ root,
                       short* __restrict__ Bp, int nk32, int krel){
  int tid = blockIdx.x * 256 + threadIdx.x;
  if (tid >= nk32 * 512) return;
  int lane = tid & 63;
  int nf   = (tid >> 6) & 7;
  int k32  = tid >> 9;
  int col  = nf * 16 + (lane & 15);
  short vals[8];
#pragma unroll
  for (int i = 0; i < 8; ++i){
    int kk = k32 * 32 + ((lane >> 4) << 3) + i;
    float f = (kk < krel) ? Wrel[(size_t)kk * 128 + col]
                          : root[(size_t)(kk - krel) * 128 + col];
    vals[i] = (short)f2bf(f);
  }
  *(bf16x8*)(Bp + (size_t)tid * 8) = *(const bf16x8*)vals;
}

// ---------------- CSR build (relation-major: seg = r*NN + dst) -------------
__global__ void count_k(const int* __restrict__ dst, const int* __restrict__ et,
                        u32* __restrict__ cnt){
  int e = blockIdx.x * 256 + threadIdx.x;
  if (e >= EE) return;
  atomicAdd(&cnt[(size_t)et[e] * NN + dst[e]], 1u);
}

__global__ void scan1_k(const u32* __restrict__ cnt, u32* __restrict__ offs, u32* __restrict__ bsum){
  __shared__ u32 s[512];
  int t = threadIdx.x;                       // 256 threads
  int base = blockIdx.x * 1024 + t * 4;
  u32 loc[4]; u32 sum = 0;
#pragma unroll
  for (int i = 0; i < 4; ++i){ loc[i] = (base + i < NSEG) ? cnt[base + i] : 0u; sum += loc[i]; }
  int pb = 0;
  s[t] = sum; __syncthreads();
  for (int off = 1; off < 256; off <<= 1){
    u32 v = s[pb * 256 + t];
    if (t >= off) v += s[pb * 256 + t - off];
    s[(pb ^ 1) * 256 + t] = v; pb ^= 1; __syncthreads();
  }
  u32 incl = s[pb * 256 + t];
  u32 excl = incl - sum;
  if (t == 255) bsum[blockIdx.x] = incl;
  u32 run = excl;
#pragma unroll
  for (int i = 0; i < 4; ++i){ if (base + i < NSEG) offs[base + i] = run; run += loc[i]; }
}

__global__ void scan2_k(u32* __restrict__ bsum){
  __shared__ u32 s[1024];
  int t = threadIdx.x;                       // 512 threads
  u32 v = (t < NB_SCAN) ? bsum[t] : 0u;
  int pb = 0;
  s[t] = v; __syncthreads();
  for (int off = 1; off < 512; off <<= 1){
    u32 x = s[pb * 512 + t];
    if (t >= off) x += s[pb * 512 + t - off];
    s[(pb ^ 1) * 512 + t] = x; pb ^= 1; __syncthreads();
  }
  u32 incl = s[pb * 512 + t];
  if (t < NB_SCAN) bsum[t] = incl - v;       // exclusive
}

__global__ void scan3_k(u32* __restrict__ offs, const u32* __restrict__ bsum){
  int t = threadIdx.x;
  int base = blockIdx.x * 1024 + t * 4;
  u32 add = bsum[blockIdx.x];
#pragma unroll
  for (int i = 0; i < 4; ++i){ if (base + i < NSEG) offs[base + i] += add; }
  if (blockIdx.x == 0 && t == 0) offs[NSEG] = EE;
}

// fill: reuse cnt as cursor (atomicSub)
__global__ void fill_k(const int* __restrict__ src, const int* __restrict__ dst,
                       const int* __restrict__ et, const u32* __restrict__ offs,
                       u32* __restrict__ cnt, int* __restrict__ elist){
  int e = blockIdx.x * 256 + threadIdx.x;
  if (e >= EE) return;
  int s = et[e] * NN + dst[e];
  u32 p = atomicSub(&cnt[s], 1u);
  elist[offs[s] + p - 1] = src[e];
}

// ------- per-(relation,dst) mean aggregation -> a[R][NN][128] bf16 ----------
// 8-lane group per segment, 32 segments/block; lane owns 32 B of the row.
__launch_bounds__(256, 8)
__global__ void agg_k(const u32* __restrict__ offs, const int* __restrict__ elist,
                      const unsigned short* __restrict__ h, unsigned short* __restrict__ a){
  int t = threadIdx.x;
  int g = t >> 3, ll8 = t & 7;
  int seg = blockIdx.x * 32 + g;
  u32 beg = offs[seg], end = offs[seg + 1];
  float s[16];
#pragma unroll
  for (int i = 0; i < 16; ++i) s[i] = 0.f;
  const unsigned short* hb = h + (size_t)ll8 * 16;
  u32 e = beg;
  for (; e + 2 <= end; e += 2){
    int s0 = elist[e], s1 = elist[e + 1];
    const unsigned short* r0 = hb + (size_t)s0 * 128;
    const unsigned short* r1 = hb + (size_t)s1 * 128;
    u32x4 p00 = *(const u32x4*)r0, p01 = *(const u32x4*)(r0 + 8);
    u32x4 p10 = *(const u32x4*)r1, p11 = *(const u32x4*)(r1 + 8);
#pragma unroll
    for (int i = 0; i < 4; ++i){
      s[2*i]     += __uint_as_float(p00[i] << 16)         + __uint_as_float(p10[i] << 16);
      s[2*i+1]   += __uint_as_float(p00[i] & 0xffff0000u) + __uint_as_float(p10[i] & 0xffff0000u);
      s[8+2*i]   += __uint_as_float(p01[i] << 16)         + __uint_as_float(p11[i] << 16);
      s[8+2*i+1] += __uint_as_float(p01[i] & 0xffff0000u) + __uint_as_float(p11[i] & 0xffff0000u);
    }
  }
  if (e < end){
    int s0 = elist[e];
    const unsigned short* r0 = hb + (size_t)s0 * 128;
    u32x4 p00 = *(const u32x4*)r0, p01 = *(const u32x4*)(r0 + 8);
#pragma unroll
    for (int i = 0; i < 4; ++i){
      s[2*i]     += __uint_as_float(p00[i] << 16);
      s[2*i+1]   += __uint_as_float(p00[i] & 0xffff0000u);
      s[8+2*i]   += __uint_as_float(p01[i] << 16);
      s[8+2*i+1] += __uint_as_float(p01[i] & 0xffff0000u);
    }
  }
  u32 deg = end - beg;
  if (deg){
    float inv = 1.f / (float)deg;
#pragma unroll
    for (int i = 0; i < 16; ++i) s[i] *= inv;
  }
  u32x4 o0, o1;
#pragma unroll
  for (int i = 0; i < 4; ++i){
    o0[i] = (u32)f2bf(s[2*i])   | ((u32)f2bf(s[2*i+1])   << 16);
    o1[i] = (u32)f2bf(s[8+2*i]) | ((u32)f2bf(s[8+2*i+1]) << 16);
  }
  unsigned short* ap = a + (size_t)seg * 128 + ll8 * 16;
  *(u32x4*)ap = o0;
  *(u32x4*)(ap + 8) = o1;
}

// ---------------- res projection: resb = bf16(x @ res_w + res_b) ----------
__launch_bounds__(256, 4)
__global__ void resg_k(const unsigned short* __restrict__ xb, const short* __restrict__ Bp,
                       const float* __restrict__ rb, unsigned short* __restrict__ resb){
  const int tid = threadIdx.x;
  const int w = tid >> 6, l = tid & 63;
  const int sub = l >> 4, llr = l & 15;
  const int rowbase = blockIdx.x * 64 + w * 16;
  int vr = rowbase + llr; if (vr > NN - 1) vr = NN - 1;
  f32x4 acc[8] = {};
#pragma unroll
  for (int t = 0; t < 4; ++t){
    bf16x8 af = *(const bf16x8*)(xb + (size_t)vr * 128 + (t * 4 + sub) * 8);
    const short* bb = Bp + (size_t)(t * 8) * 512 + l * 8;
#pragma unroll
    for (int nf = 0; nf < 8; ++nf){
      bf16x8 bq = *(const bf16x8*)(bb + nf * 512);
      acc[nf] = __builtin_amdgcn_mfma_f32_16x16x32_bf16(af, bq, acc[nf], 0, 0, 0);
    }
  }
  const int lr = l >> 4, lc = l & 15;
#pragma unroll
  for (int nf = 0; nf < 8; ++nf){
    int col = nf * 16 + lc;
    float bv = rb[col];
#pragma unroll
    for (int r = 0; r < 4; ++r){
      int row = rowbase + lr * 4 + r;
      if (row < NN) resb[(size_t)row * 128 + col] = f2bf(acc[nf][r] + bv);
    }
  }
}

// -------- MFMA GEMM, m97-style: async global_load_lds staging + 2 barriers --
// BM=64, BN=128 (full), BK=64. 4 waves: wave (wm,wn) owns 32 rows x 64 cols.
// LDS: A-tile [8 q][64 row][16B] (4096 shorts) + B-slice packed (8192 shorts).
// Per kt: 6 fire-and-forget GLD16 issues, sync (vmcnt drain), 12 ds_read_b128
// + 16 MFMA per wave, sync. No per-wave global-load->use chains.
template<int OUTMODE>
__launch_bounds__(256, 3)
__global__ void gemm_k(const unsigned short* __restrict__ Aa,   // [R][NN][128]
                       const unsigned short* __restrict__ Ah,   // [NN][128]
                       const short* __restrict__ Bp,            // 18*8192 shorts packed
                       const float* __restrict__ bias,
                       const unsigned short* __restrict__ resb,
                       float* __restrict__ outf, unsigned short* __restrict__ outb){
  __shared__ short lds[12288];               // 24 KB: A 4096 | B 8192
  const int tid = threadIdx.x;
  const int w = tid >> 6, l = tid & 63;
  const int wm = w >> 1, wn = w & 1;
  const int sub = l >> 4, llr = l & 15;
  const int mbase = blockIdx.x * 64;
  const size_t plane = (size_t)NN * 128;
  f32x4 acc[2][4] = {};

  int arow = mbase + l; if (arow > NN - 1) arow = NN - 1;   // staging row clamp

#pragma unroll 1
  for (int kt = 0; kt < 18; ++kt){
    const unsigned short* abase = (kt < 16)
        ? Aa + (size_t)(kt >> 1) * plane + (size_t)(kt & 1) * 64
        : Ah + (size_t)(kt - 16) * 64;
    // A-tile: 2 issues; chunk c = i*256+tid -> q=c>>6, row=c&63; LDS [q][row]
    GLD16(abase + (size_t)arow * 128 + w * 8,       lds + (size_t)(w * 64) * 8);
    GLD16(abase + (size_t)arow * 128 + (4 + w) * 8, lds + (size_t)(256 + w * 64) * 8);
    // B-slice: 4 issues, contiguous copy of 16 KB packed fragments
    const short* bsrc = Bp + (size_t)kt * 8192;
#pragma unroll
    for (int i = 0; i < 4; ++i)
      GLD16(bsrc + (size_t)(i * 256 + tid) * 8, lds + (size_t)(4096 + (i * 256 + w * 64) * 8));
    __syncthreads();
#pragma unroll
    for (int t = 0; t < 2; ++t){
      bf16x8 af0 = *(const bf16x8*)(lds + (size_t)(((t * 4 + sub) * 64) + wm * 32 + llr) * 8);
      bf16x8 af1 = *(const bf16x8*)(lds + (size_t)(((t * 4 + sub) * 64) + wm * 32 + 16 + llr) * 8);
#pragma unroll
      for (int nf = 0; nf < 4; ++nf){
        bf16x8 bq = *(const bf16x8*)(lds + (size_t)(4096 + (t * 8 + wn * 4 + nf) * 512 + l * 8));
        acc[0][nf] = __builtin_amdgcn_mfma_f32_16x16x32_bf16(af0, bq, acc[0][nf], 0, 0, 0);
        acc[1][nf] = __builtin_amdgcn_mfma_f32_16x16x32_bf16(af1, bq, acc[1][nf], 0, 0, 0);
      }
    }
    __syncthreads();
  }

  const int lr = l >> 4, lc = l & 15;
#pragma unroll
  for (int mf = 0; mf < 2; ++mf){
#pragma unroll
    for (int nf = 0; nf < 4; ++nf){
      int col = wn * 64 + nf * 16 + lc;
      float bv = bias[col];
#pragma unroll
      for (int r = 0; r < 4; ++r){
        int row = mbase + wm * 32 + mf * 16 + lr * 4 + r;
        if (row < NN){
          float v = acc[mf][nf][r] + bv;
          v = bf2f(resb[(size_t)row * 128 + col]) + fmaxf(v, 0.f);
          if (OUTMODE == 1) outb[(size_t)row * 128 + col] = f2bf(v);
          else              outf[(size_t)row * 128 + col] = v;
        }
      }
    }
  }
}

extern "C" void kernel_launch(void* const* d_in, const int* in_sizes, int n_in,
                              void* d_out, int out_size, void* d_ws, size_t ws_size,
                              hipStream_t stream){
  const float* x  = (const float*)d_in[0];
  const int*   ei = (const int*)d_in[1];
  const int*   et = (const int*)d_in[2];
  const float* W1 = (const float*)d_in[3];
  const float* r1 = (const float*)d_in[4];
  const float* b1 = (const float*)d_in[5];
  const float* W2 = (const float*)d_in[6];
  const float* r2 = (const float*)d_in[7];
  const float* b2 = (const float*)d_in[8];
  const float* W3 = (const float*)d_in[9];
  const float* r3 = (const float*)d_in[10];
  const float* b3 = (const float*)d_in[11];
  const float* rw = (const float*)d_in[12];
  const float* rb = (const float*)d_in[13];
  const int* srcv = ei;
  const int* dstv = ei + EE;

  char* p = (char*)d_ws;
  auto take = [&](size_t b)->char*{ char* q = p; p += (b + 255) & ~(size_t)255; return q; };
  unsigned short* a    = (unsigned short*)take((size_t)NN * 1024 * 2);  // [R][NN][128]
  unsigned short* xb   = (unsigned short*)take((size_t)NN * 128 * 2);
  unsigned short* h1   = (unsigned short*)take((size_t)NN * 128 * 2);
  unsigned short* h2   = (unsigned short*)take((size_t)NN * 128 * 2);
  unsigned short* resb = (unsigned short*)take((size_t)NN * 128 * 2);
  short* Bp1 = (short*)take(36 * 4096 * 2);
  short* Bp2 = (short*)take(36 * 4096 * 2);
  short* Bp3 = (short*)take(36 * 4096 * 2);
  short* BpR = (short*)take(4 * 4096 * 2);
  u32* cnt   = (u32*)take((size_t)NSEG * 4);
  u32* offs  = (u32*)take((size_t)(NSEG + 1) * 4);
  int* elist = (int*)take((size_t)EE * 4);
  u32* bsum  = (u32*)take((size_t)NB_SCAN * 4);

  hipMemsetAsync(cnt, 0, (size_t)NSEG * 4, stream);

  // conversions + weight packing (once)
  cvt_k<<<(NN * 128 / 4 + 255) / 256, 256, 0, stream>>>(x, xb, NN * 128 / 4);
  pack_k<<<(36 * 512 + 255) / 256, 256, 0, stream>>>(W1, r1, Bp1, 36, 1024);
  pack_k<<<(36 * 512 + 255) / 256, 256, 0, stream>>>(W2, r2, Bp2, 36, 1024);
  pack_k<<<(36 * 512 + 255) / 256, 256, 0, stream>>>(W3, r3, Bp3, 36, 1024);
  pack_k<<<(4 * 512 + 255) / 256, 256, 0, stream>>>(nullptr, rw, BpR, 4, 0);

  // CSR over segments (etype*NN + dst), once for all layers
  count_k<<<(EE + 255) / 256, 256, 0, stream>>>(dstv, et, cnt);
  scan1_k<<<NB_SCAN, 256, 0, stream>>>(cnt, offs, bsum);
  scan2_k<<<1, 512, 0, stream>>>(bsum);
  scan3_k<<<NB_SCAN, 256, 0, stream>>>(offs, bsum);
  fill_k<<<(EE + 255) / 256, 256, 0, stream>>>(srcv, dstv, et, offs, cnt, elist);

  const int GB = (NN + 63) / 64;  // 782

  // res = bf16(x @ res_w + res_b)
  resg_k<<<GB, 256, 0, stream>>>(xb, BpR, rb, resb);

  // layer 1
  agg_k<<<NSEG / 32, 256, 0, stream>>>(offs, elist, xb, a);
  gemm_k<1><<<GB, 256, 0, stream>>>(a, xb, Bp1, b1, resb, nullptr, h1);
  // layer 2
  agg_k<<<NSEG / 32, 256, 0, stream>>>(offs, elist, h1, a);
  gemm_k<1><<<GB, 256, 0, stream>>>(a, h1, Bp2, b2, resb, nullptr, h2);
  // layer 3
  agg_k<<<NSEG / 32, 256, 0, stream>>>(offs, elist, h2, a);
  gemm_k<2><<<GB, 256, 0, stream>>>(a, h2, Bp3, b3, resb, (float*)d_out, nullptr);
}